// Round 1
// baseline (1750.961 us; speedup 1.0000x reference)
//
#include <hip/hip_runtime.h>
#include <math.h>

// ---------------- init: e0=e1=e2=emb0, out[0..3)=emb0 ----------------
__global__ void init_k(const float* __restrict__ emb0, float* __restrict__ e0,
                       float* __restrict__ e1, float* __restrict__ e2,
                       float* __restrict__ out, size_t nd) {
  size_t i = (size_t)blockIdx.x * blockDim.x + threadIdx.x;
  size_t stride = (size_t)gridDim.x * blockDim.x;
  for (; i < nd; i += stride) {
    float v = emb0[i];
    e0[i] = v; e1[i] = v; e2[i] = v;
    out[i] = v; out[nd + i] = v; out[2 * nd + i] = v;
  }
}

// ---------------- CSR build ----------------
__global__ void hist_k(const int* __restrict__ h, int* __restrict__ deg, int E) {
  int i = blockIdx.x * blockDim.x + threadIdx.x;
  if (i < E) atomicAdd(&deg[h[i]], 1);
}

__global__ void scanA_k(const int* __restrict__ deg, int* __restrict__ rp,
                        int* __restrict__ sums, int N) {
  __shared__ int s[1024];
  int i = blockIdx.x * 1024 + threadIdx.x;
  int v = (i < N) ? deg[i] : 0;
  s[threadIdx.x] = v;
  __syncthreads();
  for (int off = 1; off < 1024; off <<= 1) {
    int t = (threadIdx.x >= (unsigned)off) ? s[threadIdx.x - off] : 0;
    __syncthreads();
    s[threadIdx.x] += t;
    __syncthreads();
  }
  if (i < N) rp[i] = s[threadIdx.x] - v;     // exclusive, pre-offset
  if (threadIdx.x == 1023) sums[blockIdx.x] = s[1023];
}

__global__ void scanB_k(int* sums, int nch) {
  if (threadIdx.x == 0 && blockIdx.x == 0) {
    int run = 0;
    for (int c = 0; c < nch; c++) { int t = sums[c]; sums[c] = run; run += t; }
  }
}

__global__ void scanC_k(int* __restrict__ rp, int* __restrict__ cur,
                        const int* __restrict__ sums, int N, int E) {
  int i = blockIdx.x * blockDim.x + threadIdx.x;
  if (i < N) {
    int v = rp[i] + sums[i >> 10];
    rp[i] = v; cur[i] = v;
  } else if (i == N) {
    rp[N] = E;
  }
}

__global__ void fill_k(const int* __restrict__ h, int* __restrict__ cur,
                       int* __restrict__ perm, int E) {
  int i = blockIdx.x * blockDim.x + threadIdx.x;
  if (i < E) {
    int pos = atomicAdd(&cur[h[i]], 1);
    perm[pos] = i;
  }
}

// ------- Xh|Xt projection: xht[n][0:64]=e@W1h, xht[n][64:128]=e@W1t -------
__global__ __launch_bounds__(256) void xht_k(const float* __restrict__ e,
                                             const float* __restrict__ W,  // [128][64]
                                             float* __restrict__ xht, int N) {
  __shared__ float w[128 * 64];
  for (int j = threadIdx.x; j < 128 * 64; j += 256) w[j] = W[j];
  __syncthreads();
  int n = blockIdx.x * 4 + (threadIdx.x >> 6);
  if (n >= N) return;
  int d = threadIdx.x & 63;
  float ed = e[(size_t)n * 64 + d];
  float ah = 0.f, at = 0.f;
#pragma unroll
  for (int k = 0; k < 64; k++) {
    float ek = __shfl(ed, k, 64);
    ah = fmaf(ek, w[k * 64 + d], ah);
    at = fmaf(ek, w[(k + 64) * 64 + d], at);
  }
  xht[(size_t)n * 128 + d] = ah;
  xht[(size_t)n * 128 + 64 + d] = at;
}

// ------- per-edge logits + gumbel sigmoid: w[e] -------
__global__ __launch_bounds__(256) void edgew_k(const float* __restrict__ xht,
    const int* __restrict__ h_idx, const int* __restrict__ t_idx,
    const float* __restrict__ b1, const float* __restrict__ W2,
    const float* __restrict__ b2, const float* __restrict__ gum,
    float* __restrict__ w, int E) {
  long long gid = (long long)blockIdx.x * 256 + threadIdx.x;
  int eg = (int)(gid >> 4);
  if (eg >= E) return;
  int l = threadIdx.x & 15;
  int h = h_idx[eg], t = t_idx[eg];
  const float4 xh = *(const float4*)(xht + (size_t)h * 128 + l * 4);
  const float4 xt = *(const float4*)(xht + (size_t)t * 128 + 64 + l * 4);
  const float4 bb = *(const float4*)(b1 + l * 4);
  const float4 ww = *(const float4*)(W2 + l * 4);
  float p = fmaxf(xh.x + xt.x + bb.x, 0.f) * ww.x
          + fmaxf(xh.y + xt.y + bb.y, 0.f) * ww.y
          + fmaxf(xh.z + xt.z + bb.z, 0.f) * ww.z
          + fmaxf(xh.w + xt.w + bb.w, 0.f) * ww.w;
  p += __shfl_xor(p, 1, 64);
  p += __shfl_xor(p, 2, 64);
  p += __shfl_xor(p, 4, 64);
  p += __shfl_xor(p, 8, 64);
  if (l == 0) {
    float x = gum[eg] + p + b2[0];
    w[eg] = 1.f / (1.f + expf(-x));
  }
}

// ------- per-node row-sum of w and reciprocal -------
__global__ void dinv_k(const int* __restrict__ rp, const int* __restrict__ perm,
                       const float* __restrict__ w, float* __restrict__ dinv, int N) {
  int n = blockIdx.x * blockDim.x + threadIdx.x;
  if (n >= N) return;
  float s = 0.f;
  int jb = rp[n], je = rp[n + 1];
  for (int j = jb; j < je; j++) s += w[perm[j]];
  dinv[n] = (s > 0.f) ? 1.f / s : 0.f;
}

// ------- node MLP + gate: y = sigmoid(gum + relu(e@W1+b1)@W2+b2) * e -------
__global__ __launch_bounds__(256) void mlp2_k(const float* __restrict__ e,
    const float* __restrict__ W1, const float* __restrict__ b1,
    const float* __restrict__ W2, const float* __restrict__ b2,
    const float* __restrict__ gum, float* __restrict__ y, int N) {
  __shared__ float w1[64 * 64];
  __shared__ float w2[64 * 64];
  for (int j = threadIdx.x; j < 4096; j += 256) { w1[j] = W1[j]; w2[j] = W2[j]; }
  __syncthreads();
  int n = blockIdx.x * 4 + (threadIdx.x >> 6);
  if (n >= N) return;
  int d = threadIdx.x & 63;
  float ed = e[(size_t)n * 64 + d];
  float a1 = b1[d];
#pragma unroll
  for (int k = 0; k < 64; k++) {
    float ek = __shfl(ed, k, 64);
    a1 = fmaf(ek, w1[k * 64 + d], a1);
  }
  float hd = fmaxf(a1, 0.f);
  float a2 = b2[d];
#pragma unroll
  for (int k = 0; k < 64; k++) {
    float hk = __shfl(hd, k, 64);
    a2 = fmaf(hk, w2[k * 64 + d], a2);
  }
  float x = gum[(size_t)n * 64 + d] + a2;
  float gate = 1.f / (1.f + expf(-x));
  y[(size_t)n * 64 + d] = gate * ed;
}

// ------- CSR SpMM fused with residual + running-sum update -------
// enext[n] = sum_j evals[e]*src[t]  (*rowscale[n])  + ecur[n];  sout[n] += enext[n]
__global__ __launch_bounds__(256) void spmm_k(const int* __restrict__ rp,
    const int* __restrict__ perm, const int* __restrict__ t_idx,
    const float* __restrict__ evals, const float* __restrict__ rowscale,
    const float* __restrict__ src, const float* __restrict__ ecur,
    float* __restrict__ enext, float* __restrict__ sout, int N) {
  int n = blockIdx.x * 4 + (threadIdx.x >> 6);
  if (n >= N) return;
  int d = threadIdx.x & 63;
  int jb = rp[n], je = rp[n + 1];
  float acc = 0.f;
  for (int j = jb; j < je; j++) {
    int e = perm[j];
    int t = t_idx[e];
    acc = fmaf(evals[e], src[(size_t)t * 64 + d], acc);
  }
  if (rowscale) acc *= rowscale[n];
  size_t o = (size_t)n * 64 + d;
  float en = acc + ecur[o];
  enext[o] = en;
  sout[o] += en;
}

extern "C" void kernel_launch(void* const* d_in, const int* in_sizes, int n_in,
                              void* d_out, int out_size, void* d_ws, size_t ws_size,
                              hipStream_t stream) {
  const float* emb0        = (const float*)d_in[0];
  const int*   h_idx       = (const int*)d_in[1];
  const int*   t_idx       = (const int*)d_in[2];
  const float* G_values    = (const float*)d_in[3];
  const float* edge_gumbel = (const float*)d_in[4];
  const float* emb_gumbel  = (const float*)d_in[5];
  const float* edge_W1     = (const float*)d_in[6];
  const float* edge_b1     = (const float*)d_in[7];
  const float* edge_W2     = (const float*)d_in[8];
  const float* edge_b2     = (const float*)d_in[9];
  const float* emb_W1      = (const float*)d_in[10];
  const float* emb_b1      = (const float*)d_in[11];
  const float* emb_W2      = (const float*)d_in[12];
  const float* emb_b2      = (const float*)d_in[13];

  const int D = 64;
  const int N = in_sizes[0] / D;
  const int E = in_sizes[1];
  const int L = in_sizes[4] / E;
  const size_t ND = (size_t)N * D;

  // ---- carve workspace ----
  char* p = (char*)d_ws;
  auto alloc = [&](size_t bytes) -> char* {
    char* r = p;
    p += (bytes + 255) & ~(size_t)255;
    return r;
  };
  float* e0a   = (float*)alloc(ND * 4);
  float* e0b   = (float*)alloc(ND * 4);
  float* e1a   = (float*)alloc(ND * 4);
  float* e1b   = (float*)alloc(ND * 4);
  float* e2a   = (float*)alloc(ND * 4);
  float* e2b   = (float*)alloc(ND * 4);
  float* xht   = (float*)alloc(ND * 8);       // [N][128]; reused as y2 later in layer
  float* wbuf  = (float*)alloc((size_t)E * 4);
  float* dinvb = (float*)alloc((size_t)N * 4);
  int*   deg   = (int*)alloc((size_t)N * 4);
  int*   cur   = (int*)alloc((size_t)N * 4);
  int*   rp    = (int*)alloc(((size_t)N + 1) * 4);
  int*   perm  = (int*)alloc((size_t)E * 4);
  int*   sums  = (int*)alloc(1024 * 4);
  float* y2    = xht;

  float* out = (float*)d_out;

  // ---- init + CSR build ----
  init_k<<<2048, 256, 0, stream>>>(emb0, e0a, e1a, e2a, out, ND);
  hipMemsetAsync(deg, 0, (size_t)N * 4, stream);
  hist_k<<<(E + 255) / 256, 256, 0, stream>>>(h_idx, deg, E);
  int nch = (N + 1023) / 1024;
  scanA_k<<<nch, 1024, 0, stream>>>(deg, rp, sums, N);
  scanB_k<<<1, 64, 0, stream>>>(sums, nch);
  scanC_k<<<(N + 256) / 256, 256, 0, stream>>>(rp, cur, sums, N, E);
  fill_k<<<(E + 255) / 256, 256, 0, stream>>>(h_idx, cur, perm, E);

  float *e0c = e0a, *e0n = e0b, *e1c = e1a, *e1n = e1b, *e2c = e2a, *e2n = e2b;
  int nb4 = (N + 3) / 4;

  for (int i = 0; i < L; i++) {
    // branch 1 prep: per-node projections, per-edge weights, row normalizer
    xht_k<<<nb4, 256, 0, stream>>>(e1c, edge_W1 + (size_t)i * 128 * 64, xht, N);
    edgew_k<<<(int)(((long long)E * 16 + 255) / 256), 256, 0, stream>>>(
        xht, h_idx, t_idx, edge_b1 + (size_t)i * 64, edge_W2 + (size_t)i * 64,
        edge_b2 + i, edge_gumbel + (size_t)i * E, wbuf, E);
    dinv_k<<<(N + 255) / 256, 256, 0, stream>>>(rp, perm, wbuf, dinvb, N);

    // branch 0: plain normalized propagation
    spmm_k<<<nb4, 256, 0, stream>>>(rp, perm, t_idx, G_values, nullptr,
                                    e0c, e0c, e0n, out, N);
    // branch 1: learned edge reweighting
    spmm_k<<<nb4, 256, 0, stream>>>(rp, perm, t_idx, wbuf, dinvb,
                                    e1c, e1c, e1n, out + ND, N);
    // branch 2: learned feature gating (y2 aliases xht; xht no longer needed)
    mlp2_k<<<nb4, 256, 0, stream>>>(e2c, emb_W1 + (size_t)i * 4096,
                                    emb_b1 + (size_t)i * 64,
                                    emb_W2 + (size_t)i * 4096,
                                    emb_b2 + (size_t)i * 64,
                                    emb_gumbel + (size_t)i * ND, y2, N);
    spmm_k<<<nb4, 256, 0, stream>>>(rp, perm, t_idx, G_values, nullptr,
                                    y2, e2c, e2n, out + 2 * ND, N);

    float* tmp;
    tmp = e0c; e0c = e0n; e0n = tmp;
    tmp = e1c; e1c = e1n; e1n = tmp;
    tmp = e2c; e2c = e2n; e2n = tmp;
  }
}

// Round 2
// 718.516 us; speedup vs baseline: 2.4369x; 2.4369x over previous
//
#include <hip/hip_runtime.h>
#include <math.h>

#define ST_E 68    // padded stride for 64-col fp32 tiles (272B, 16B-aligned, 2-way max)
#define ST_W 68    // 64-col weights
#define ST_WX 132  // 128-col weights (528B, 16B-aligned)

__device__ __forceinline__ float4 f4z() { return make_float4(0.f, 0.f, 0.f, 0.f); }
__device__ __forceinline__ void fma4(float4& a, float s, const float4& v) {
  a.x = fmaf(s, v.x, a.x); a.y = fmaf(s, v.y, a.y);
  a.z = fmaf(s, v.z, a.z); a.w = fmaf(s, v.w, a.w);
}
__device__ __forceinline__ float4 add4(const float4& a, const float4& b) {
  return make_float4(a.x + b.x, a.y + b.y, a.z + b.z, a.w + b.w);
}

// ---------------- init: e0=e1=e2=emb0, out[0..3)=emb0 ----------------
__global__ void init_k(const float* __restrict__ emb0, float* __restrict__ e0,
                       float* __restrict__ e1, float* __restrict__ e2,
                       float* __restrict__ out, size_t nd) {
  size_t i = (size_t)blockIdx.x * blockDim.x + threadIdx.x;
  size_t stride = (size_t)gridDim.x * blockDim.x;
  for (; i < nd; i += stride) {
    float v = emb0[i];
    e0[i] = v; e1[i] = v; e2[i] = v;
    out[i] = v; out[nd + i] = v; out[2 * nd + i] = v;
  }
}

// ---------------- CSR build ----------------
__global__ void hist_k(const int* __restrict__ h, int* __restrict__ deg, int E) {
  int i = blockIdx.x * blockDim.x + threadIdx.x;
  if (i < E) atomicAdd(&deg[h[i]], 1);
}

__global__ void scanA_k(const int* __restrict__ deg, int* __restrict__ rp,
                        int* __restrict__ sums, int N) {
  __shared__ int s[1024];
  int i = blockIdx.x * 1024 + threadIdx.x;
  int v = (i < N) ? deg[i] : 0;
  s[threadIdx.x] = v;
  __syncthreads();
  for (int off = 1; off < 1024; off <<= 1) {
    int t = (threadIdx.x >= (unsigned)off) ? s[threadIdx.x - off] : 0;
    __syncthreads();
    s[threadIdx.x] += t;
    __syncthreads();
  }
  if (i < N) rp[i] = s[threadIdx.x] - v;
  if (threadIdx.x == 1023) sums[blockIdx.x] = s[1023];
}

__global__ void scanB_k(int* sums, int nch) {
  if (threadIdx.x == 0 && blockIdx.x == 0) {
    int run = 0;
    for (int c = 0; c < nch; c++) { int t = sums[c]; sums[c] = run; run += t; }
  }
}

__global__ void scanC_k(int* __restrict__ rp, int* __restrict__ cur,
                        const int* __restrict__ sums, int N, int E) {
  int i = blockIdx.x * blockDim.x + threadIdx.x;
  if (i < N) {
    int v = rp[i] + sums[i >> 10];
    rp[i] = v; cur[i] = v;
  } else if (i == N) {
    rp[N] = E;
  }
}

__global__ void fill_k(const int* __restrict__ h, int* __restrict__ cur,
                       int* __restrict__ perm, int E) {
  int i = blockIdx.x * blockDim.x + threadIdx.x;
  if (i < E) {
    int pos = atomicAdd(&cur[h[i]], 1);
    perm[pos] = i;
  }
}

// ------- pre-gather edge data into CSR slot order (layer-invariant) -------
__global__ void pregather_k(const int* __restrict__ perm, const int* __restrict__ h_idx,
                            const int* __restrict__ t_idx, const float* __restrict__ G,
                            int* __restrict__ crow, int* __restrict__ ct,
                            float* __restrict__ cg, int E) {
  int j = blockIdx.x * blockDim.x + threadIdx.x;
  if (j < E) {
    int pe = perm[j];
    crow[j] = h_idx[pe];
    ct[j] = t_idx[pe];
    cg[j] = G[pe];
  }
}

// ------- xht: [N][128] = e @ [W1h | W1t] (register-tiled GEMM) -------
__global__ __launch_bounds__(256) void xht_k(const float* __restrict__ e,
                                             const float* __restrict__ W,  // [128][64]
                                             float* __restrict__ xht, int N) {
  __shared__ float et[64 * ST_E];
  __shared__ float wl[64 * ST_WX];
  int tid = threadIdx.x;
  int n0 = blockIdx.x * 64;
  for (int i = tid; i < 64 * 16; i += 256) {
    int r = i >> 4, c4 = (i & 15) * 4;
    float4 v = (n0 + r < N) ? *(const float4*)(e + (size_t)(n0 + r) * 64 + c4) : f4z();
    *(float4*)(et + r * ST_E + c4) = v;
  }
  for (int i = tid; i < 128 * 16; i += 256) {
    int r = i >> 4, c4 = (i & 15) * 4;
    float4 v = *(const float4*)(W + r * 64 + c4);
    if (r < 64) *(float4*)(wl + r * ST_WX + c4) = v;
    else        *(float4*)(wl + (r - 64) * ST_WX + 64 + c4) = v;
  }
  __syncthreads();
  int rg = tid >> 4, tx = tid & 15;
  int s2 = (tx >> 2) * 2;
  float acc[4][8];
#pragma unroll
  for (int i = 0; i < 4; i++)
#pragma unroll
    for (int j = 0; j < 8; j++) acc[i][j] = 0.f;
#pragma unroll 4
  for (int k = 0; k < 64; k++) {
    int kk = (k + s2) & 63;
    float a0 = et[(rg * 4 + 0) * ST_E + kk];
    float a1 = et[(rg * 4 + 1) * ST_E + kk];
    float a2 = et[(rg * 4 + 2) * ST_E + kk];
    float a3 = et[(rg * 4 + 3) * ST_E + kk];
    float4 b0 = *(const float4*)(wl + kk * ST_WX + tx * 8);
    float4 b1 = *(const float4*)(wl + kk * ST_WX + tx * 8 + 4);
    acc[0][0] = fmaf(a0, b0.x, acc[0][0]); acc[0][1] = fmaf(a0, b0.y, acc[0][1]);
    acc[0][2] = fmaf(a0, b0.z, acc[0][2]); acc[0][3] = fmaf(a0, b0.w, acc[0][3]);
    acc[0][4] = fmaf(a0, b1.x, acc[0][4]); acc[0][5] = fmaf(a0, b1.y, acc[0][5]);
    acc[0][6] = fmaf(a0, b1.z, acc[0][6]); acc[0][7] = fmaf(a0, b1.w, acc[0][7]);
    acc[1][0] = fmaf(a1, b0.x, acc[1][0]); acc[1][1] = fmaf(a1, b0.y, acc[1][1]);
    acc[1][2] = fmaf(a1, b0.z, acc[1][2]); acc[1][3] = fmaf(a1, b0.w, acc[1][3]);
    acc[1][4] = fmaf(a1, b1.x, acc[1][4]); acc[1][5] = fmaf(a1, b1.y, acc[1][5]);
    acc[1][6] = fmaf(a1, b1.z, acc[1][6]); acc[1][7] = fmaf(a1, b1.w, acc[1][7]);
    acc[2][0] = fmaf(a2, b0.x, acc[2][0]); acc[2][1] = fmaf(a2, b0.y, acc[2][1]);
    acc[2][2] = fmaf(a2, b0.z, acc[2][2]); acc[2][3] = fmaf(a2, b0.w, acc[2][3]);
    acc[2][4] = fmaf(a2, b1.x, acc[2][4]); acc[2][5] = fmaf(a2, b1.y, acc[2][5]);
    acc[2][6] = fmaf(a2, b1.z, acc[2][6]); acc[2][7] = fmaf(a2, b1.w, acc[2][7]);
    acc[3][0] = fmaf(a3, b0.x, acc[3][0]); acc[3][1] = fmaf(a3, b0.y, acc[3][1]);
    acc[3][2] = fmaf(a3, b0.z, acc[3][2]); acc[3][3] = fmaf(a3, b0.w, acc[3][3]);
    acc[3][4] = fmaf(a3, b1.x, acc[3][4]); acc[3][5] = fmaf(a3, b1.y, acc[3][5]);
    acc[3][6] = fmaf(a3, b1.z, acc[3][6]); acc[3][7] = fmaf(a3, b1.w, acc[3][7]);
  }
#pragma unroll
  for (int i = 0; i < 4; i++) {
    int n = n0 + rg * 4 + i;
    if (n < N) {
      *(float4*)(xht + (size_t)n * 128 + tx * 8) =
          make_float4(acc[i][0], acc[i][1], acc[i][2], acc[i][3]);
      *(float4*)(xht + (size_t)n * 128 + tx * 8 + 4) =
          make_float4(acc[i][4], acc[i][5], acc[i][6], acc[i][7]);
    }
  }
}

// ------- per-slot edge weight (CSR order): cw[j] -------
__global__ __launch_bounds__(256) void edgew_k(const float* __restrict__ xht,
    const int* __restrict__ crow, const int* __restrict__ ct,
    const int* __restrict__ perm, const float* __restrict__ b1,
    const float* __restrict__ W2, const float* __restrict__ b2,
    const float* __restrict__ gum, float* __restrict__ cw, int E) {
  long long gid = (long long)blockIdx.x * 256 + threadIdx.x;
  int j = (int)(gid >> 4);
  if (j >= E) return;
  int l = threadIdx.x & 15;
  int h = crow[j], t = ct[j];
  const float4 xh = *(const float4*)(xht + (size_t)h * 128 + l * 4);
  const float4 xt = *(const float4*)(xht + (size_t)t * 128 + 64 + l * 4);
  const float4 bb = *(const float4*)(b1 + l * 4);
  const float4 ww = *(const float4*)(W2 + l * 4);
  float p = fmaxf(xh.x + xt.x + bb.x, 0.f) * ww.x
          + fmaxf(xh.y + xt.y + bb.y, 0.f) * ww.y
          + fmaxf(xh.z + xt.z + bb.z, 0.f) * ww.z
          + fmaxf(xh.w + xt.w + bb.w, 0.f) * ww.w;
  p += __shfl_xor(p, 1, 16);
  p += __shfl_xor(p, 2, 16);
  p += __shfl_xor(p, 4, 16);
  p += __shfl_xor(p, 8, 16);
  if (l == 0) {
    float x = gum[perm[j]] + p + b2[0];
    cw[j] = 1.f / (1.f + expf(-x));
  }
}

// ------- node MLP + gate (register-tiled): y = sigmoid(gum + relu(e@W1+b1)@W2+b2) * e -------
__global__ __launch_bounds__(256) void mlp2_k(const float* __restrict__ e,
    const float* __restrict__ W1, const float* __restrict__ b1,
    const float* __restrict__ W2, const float* __restrict__ b2,
    const float* __restrict__ gum, float* __restrict__ y, int N) {
  __shared__ float et[64 * ST_E];
  __shared__ float w1l[64 * ST_W];
  __shared__ float w2l[64 * ST_W];
  __shared__ float ht[64 * ST_E];
  int tid = threadIdx.x;
  int n0 = blockIdx.x * 64;
  for (int i = tid; i < 64 * 16; i += 256) {
    int r = i >> 4, c4 = (i & 15) * 4;
    float4 v = (n0 + r < N) ? *(const float4*)(e + (size_t)(n0 + r) * 64 + c4) : f4z();
    *(float4*)(et + r * ST_E + c4) = v;
    *(float4*)(w1l + r * ST_W + c4) = *(const float4*)(W1 + r * 64 + c4);
    *(float4*)(w2l + r * ST_W + c4) = *(const float4*)(W2 + r * 64 + c4);
  }
  __syncthreads();
  int rg = tid >> 4, tx = tid & 15;
  int s2 = (tx >> 2) * 2;
  float acc[4][4];
#pragma unroll
  for (int i = 0; i < 4; i++)
#pragma unroll
    for (int j = 0; j < 4; j++) acc[i][j] = 0.f;
#pragma unroll 4
  for (int k = 0; k < 64; k++) {
    int kk = (k + s2) & 63;
    float a0 = et[(rg * 4 + 0) * ST_E + kk];
    float a1 = et[(rg * 4 + 1) * ST_E + kk];
    float a2 = et[(rg * 4 + 2) * ST_E + kk];
    float a3 = et[(rg * 4 + 3) * ST_E + kk];
    float4 bv = *(const float4*)(w1l + kk * ST_W + tx * 4);
    acc[0][0] = fmaf(a0, bv.x, acc[0][0]); acc[0][1] = fmaf(a0, bv.y, acc[0][1]);
    acc[0][2] = fmaf(a0, bv.z, acc[0][2]); acc[0][3] = fmaf(a0, bv.w, acc[0][3]);
    acc[1][0] = fmaf(a1, bv.x, acc[1][0]); acc[1][1] = fmaf(a1, bv.y, acc[1][1]);
    acc[1][2] = fmaf(a1, bv.z, acc[1][2]); acc[1][3] = fmaf(a1, bv.w, acc[1][3]);
    acc[2][0] = fmaf(a2, bv.x, acc[2][0]); acc[2][1] = fmaf(a2, bv.y, acc[2][1]);
    acc[2][2] = fmaf(a2, bv.z, acc[2][2]); acc[2][3] = fmaf(a2, bv.w, acc[2][3]);
    acc[3][0] = fmaf(a3, bv.x, acc[3][0]); acc[3][1] = fmaf(a3, bv.y, acc[3][1]);
    acc[3][2] = fmaf(a3, bv.z, acc[3][2]); acc[3][3] = fmaf(a3, bv.w, acc[3][3]);
  }
  float4 b1v = *(const float4*)(b1 + tx * 4);
#pragma unroll
  for (int i = 0; i < 4; i++) {
    float4 hv = make_float4(fmaxf(acc[i][0] + b1v.x, 0.f), fmaxf(acc[i][1] + b1v.y, 0.f),
                            fmaxf(acc[i][2] + b1v.z, 0.f), fmaxf(acc[i][3] + b1v.w, 0.f));
    *(float4*)(ht + (rg * 4 + i) * ST_E + tx * 4) = hv;
  }
  __syncthreads();
  float acc2[4][4];
#pragma unroll
  for (int i = 0; i < 4; i++)
#pragma unroll
    for (int j = 0; j < 4; j++) acc2[i][j] = 0.f;
#pragma unroll 4
  for (int k = 0; k < 64; k++) {
    int kk = (k + s2) & 63;
    float a0 = ht[(rg * 4 + 0) * ST_E + kk];
    float a1 = ht[(rg * 4 + 1) * ST_E + kk];
    float a2 = ht[(rg * 4 + 2) * ST_E + kk];
    float a3 = ht[(rg * 4 + 3) * ST_E + kk];
    float4 bv = *(const float4*)(w2l + kk * ST_W + tx * 4);
    acc2[0][0] = fmaf(a0, bv.x, acc2[0][0]); acc2[0][1] = fmaf(a0, bv.y, acc2[0][1]);
    acc2[0][2] = fmaf(a0, bv.z, acc2[0][2]); acc2[0][3] = fmaf(a0, bv.w, acc2[0][3]);
    acc2[1][0] = fmaf(a1, bv.x, acc2[1][0]); acc2[1][1] = fmaf(a1, bv.y, acc2[1][1]);
    acc2[1][2] = fmaf(a1, bv.z, acc2[1][2]); acc2[1][3] = fmaf(a1, bv.w, acc2[1][3]);
    acc2[2][0] = fmaf(a2, bv.x, acc2[2][0]); acc2[2][1] = fmaf(a2, bv.y, acc2[2][1]);
    acc2[2][2] = fmaf(a2, bv.z, acc2[2][2]); acc2[2][3] = fmaf(a2, bv.w, acc2[2][3]);
    acc2[3][0] = fmaf(a3, bv.x, acc2[3][0]); acc2[3][1] = fmaf(a3, bv.y, acc2[3][1]);
    acc2[3][2] = fmaf(a3, bv.z, acc2[3][2]); acc2[3][3] = fmaf(a3, bv.w, acc2[3][3]);
  }
  float4 b2v = *(const float4*)(b2 + tx * 4);
#pragma unroll
  for (int i = 0; i < 4; i++) {
    int n = n0 + rg * 4 + i;
    if (n < N) {
      float4 gv = *(const float4*)(gum + (size_t)n * 64 + tx * 4);
      float4 ev = *(const float4*)(et + (rg * 4 + i) * ST_E + tx * 4);
      float4 yv;
      yv.x = ev.x / (1.f + expf(-(gv.x + acc2[i][0] + b2v.x)));
      yv.y = ev.y / (1.f + expf(-(gv.y + acc2[i][1] + b2v.y)));
      yv.z = ev.z / (1.f + expf(-(gv.z + acc2[i][2] + b2v.z)));
      yv.w = ev.w / (1.f + expf(-(gv.w + acc2[i][3] + b2v.w)));
      *(float4*)(y + (size_t)n * 64 + tx * 4) = yv;
    }
  }
}

// ------- fused 3-branch CSR SpMM + dinv + residual + running-sum -------
// group of 16 lanes per row, float4 per lane.
__global__ __launch_bounds__(256) void spmm3_k(const int* __restrict__ rp,
    const int* __restrict__ ct, const float* __restrict__ cg,
    const float* __restrict__ cw,
    const float* __restrict__ e0c, const float* __restrict__ e1c,
    const float* __restrict__ y2, const float* __restrict__ e2c,
    float* __restrict__ e0n, float* __restrict__ e1n, float* __restrict__ e2n,
    float* __restrict__ out0, float* __restrict__ out1, float* __restrict__ out2,
    int N) {
  int g = threadIdx.x >> 4;
  int l = threadIdx.x & 15;
  int n = blockIdx.x * 16 + g;
  if (n >= N) return;
  int jb = rp[n], je = rp[n + 1];
  size_t o = (size_t)n * 64 + l * 4;
  // issue epilogue loads early to overlap with gather latency
  float4 ec0 = *(const float4*)(e0c + o);
  float4 ec1 = *(const float4*)(e1c + o);
  float4 ec2 = *(const float4*)(e2c + o);
  float4 ov0 = *(const float4*)(out0 + o);
  float4 ov1 = *(const float4*)(out1 + o);
  float4 ov2 = *(const float4*)(out2 + o);
  float4 acc0 = f4z(), acc1 = f4z(), acc2 = f4z();
  float wsum = 0.f;
  for (int base = jb; base < je; base += 16) {
    int idx = base + l;
    bool valid = idx < je;
    int tv = valid ? ct[idx] : 0;
    float gv = valid ? cg[idx] : 0.f;
    float wv = valid ? cw[idx] : 0.f;
    wsum += wv;
    int cnt = min(16, je - base);
    for (int i = 0; i < cnt; i++) {
      int t = __shfl(tv, i, 16);
      float gg = __shfl(gv, i, 16);
      float ww = __shfl(wv, i, 16);
      size_t to = (size_t)t * 64 + l * 4;
      float4 v0 = *(const float4*)(e0c + to);
      float4 v1 = *(const float4*)(e1c + to);
      float4 v2 = *(const float4*)(y2 + to);
      fma4(acc0, gg, v0);
      fma4(acc1, ww, v1);
      fma4(acc2, gg, v2);
    }
  }
  wsum += __shfl_xor(wsum, 1, 16);
  wsum += __shfl_xor(wsum, 2, 16);
  wsum += __shfl_xor(wsum, 4, 16);
  wsum += __shfl_xor(wsum, 8, 16);
  float dinv = (wsum > 0.f) ? 1.f / wsum : 0.f;
  float4 en0 = add4(acc0, ec0);
  acc1.x *= dinv; acc1.y *= dinv; acc1.z *= dinv; acc1.w *= dinv;
  float4 en1 = add4(acc1, ec1);
  float4 en2 = add4(acc2, ec2);
  *(float4*)(e0n + o) = en0;
  *(float4*)(e1n + o) = en1;
  *(float4*)(e2n + o) = en2;
  *(float4*)(out0 + o) = add4(ov0, en0);
  *(float4*)(out1 + o) = add4(ov1, en1);
  *(float4*)(out2 + o) = add4(ov2, en2);
}

extern "C" void kernel_launch(void* const* d_in, const int* in_sizes, int n_in,
                              void* d_out, int out_size, void* d_ws, size_t ws_size,
                              hipStream_t stream) {
  const float* emb0        = (const float*)d_in[0];
  const int*   h_idx       = (const int*)d_in[1];
  const int*   t_idx       = (const int*)d_in[2];
  const float* G_values    = (const float*)d_in[3];
  const float* edge_gumbel = (const float*)d_in[4];
  const float* emb_gumbel  = (const float*)d_in[5];
  const float* edge_W1     = (const float*)d_in[6];
  const float* edge_b1     = (const float*)d_in[7];
  const float* edge_W2     = (const float*)d_in[8];
  const float* edge_b2     = (const float*)d_in[9];
  const float* emb_W1      = (const float*)d_in[10];
  const float* emb_b1      = (const float*)d_in[11];
  const float* emb_W2      = (const float*)d_in[12];
  const float* emb_b2      = (const float*)d_in[13];

  const int D = 64;
  const int N = in_sizes[0] / D;
  const int E = in_sizes[1];
  const int L = in_sizes[4] / E;
  const size_t ND = (size_t)N * D;

  char* p = (char*)d_ws;
  auto alloc = [&](size_t bytes) -> char* {
    char* r = p;
    p += (bytes + 255) & ~(size_t)255;
    return r;
  };
  float* e0a   = (float*)alloc(ND * 4);
  float* e0b   = (float*)alloc(ND * 4);
  float* e1a   = (float*)alloc(ND * 4);
  float* e1b   = (float*)alloc(ND * 4);
  float* e2    = (float*)alloc(ND * 4);        // in-place (branch-2 gathers from y2)
  float* xht   = (float*)alloc(ND * 8);        // [N][128]; aliased as y2 after edgew
  float* cw    = (float*)alloc((size_t)E * 4);
  float* cg    = (float*)alloc((size_t)E * 4);
  int*   ct    = (int*)alloc((size_t)E * 4);
  int*   crow  = (int*)alloc((size_t)E * 4);
  int*   deg   = (int*)alloc((size_t)N * 4);
  int*   cur   = (int*)alloc((size_t)N * 4);
  int*   rp    = (int*)alloc(((size_t)N + 1) * 4);
  int*   perm  = (int*)alloc((size_t)E * 4);
  int*   sums  = (int*)alloc(1024 * 4);
  float* y2    = xht;

  float* out = (float*)d_out;

  init_k<<<2048, 256, 0, stream>>>(emb0, e0a, e1a, e2, out, ND);
  hipMemsetAsync(deg, 0, (size_t)N * 4, stream);
  hist_k<<<(E + 255) / 256, 256, 0, stream>>>(h_idx, deg, E);
  int nch = (N + 1023) / 1024;
  scanA_k<<<nch, 1024, 0, stream>>>(deg, rp, sums, N);
  scanB_k<<<1, 64, 0, stream>>>(sums, nch);
  scanC_k<<<(N + 256) / 256, 256, 0, stream>>>(rp, cur, sums, N, E);
  fill_k<<<(E + 255) / 256, 256, 0, stream>>>(h_idx, cur, perm, E);
  pregather_k<<<(E + 255) / 256, 256, 0, stream>>>(perm, h_idx, t_idx, G_values,
                                                   crow, ct, cg, E);

  float *e0c = e0a, *e0n = e0b, *e1c = e1a, *e1n = e1b;
  int nb64 = (N + 63) / 64;
  int nb16 = (N + 15) / 16;

  for (int i = 0; i < L; i++) {
    xht_k<<<nb64, 256, 0, stream>>>(e1c, edge_W1 + (size_t)i * 128 * 64, xht, N);
    edgew_k<<<(int)(((long long)E * 16 + 255) / 256), 256, 0, stream>>>(
        xht, crow, ct, perm, edge_b1 + (size_t)i * 64, edge_W2 + (size_t)i * 64,
        edge_b2 + i, edge_gumbel + (size_t)i * E, cw, E);
    mlp2_k<<<nb64, 256, 0, stream>>>(e2, emb_W1 + (size_t)i * 4096,
                                     emb_b1 + (size_t)i * 64,
                                     emb_W2 + (size_t)i * 4096,
                                     emb_b2 + (size_t)i * 64,
                                     emb_gumbel + (size_t)i * ND, y2, N);
    spmm3_k<<<nb16, 256, 0, stream>>>(rp, ct, cg, cw,
                                      e0c, e1c, y2, e2,
                                      e0n, e1n, e2,
                                      out, out + ND, out + 2 * ND, N);
    float* tmp;
    tmp = e0c; e0c = e0n; e0n = tmp;
    tmp = e1c; e1c = e1n; e1n = tmp;
  }
}

// Round 3
// 533.991 us; speedup vs baseline: 3.2790x; 1.3456x over previous
//
#include <hip/hip_runtime.h>
#include <hip/hip_bf16.h>
#include <math.h>

#define ST_E 68    // padded stride for 64-col fp32 tiles
#define ST_W 68
#define ST_WX 132

__device__ __forceinline__ float4 f4z() { return make_float4(0.f, 0.f, 0.f, 0.f); }
__device__ __forceinline__ void fma4(float4& a, float s, const float4& v) {
  a.x = fmaf(s, v.x, a.x); a.y = fmaf(s, v.y, a.y);
  a.z = fmaf(s, v.z, a.z); a.w = fmaf(s, v.w, a.w);
}
__device__ __forceinline__ float4 add4(const float4& a, const float4& b) {
  return make_float4(a.x + b.x, a.y + b.y, a.z + b.z, a.w + b.w);
}
__device__ __forceinline__ float4 ldbf4(const unsigned short* p) {
  ushort4 u = *(const ushort4*)p;
  float4 f;
  f.x = __uint_as_float((unsigned)u.x << 16);
  f.y = __uint_as_float((unsigned)u.y << 16);
  f.z = __uint_as_float((unsigned)u.z << 16);
  f.w = __uint_as_float((unsigned)u.w << 16);
  return f;
}
__device__ __forceinline__ unsigned short f2bf(float v) {
  __hip_bfloat16 h = __float2bfloat16(v);
  return *reinterpret_cast<unsigned short*>(&h);
}
__device__ __forceinline__ void st4bf(unsigned short* p, const float4& v) {
  ushort4 u;
  u.x = f2bf(v.x); u.y = f2bf(v.y); u.z = f2bf(v.z); u.w = f2bf(v.w);
  *(ushort4*)p = u;
}

// -------- init: pk0 e0/e1 slots = bf16(emb0) --------
__global__ void init_k(const float* __restrict__ emb0, unsigned short* __restrict__ pk0,
                       int N) {
  int idx = blockIdx.x * blockDim.x + threadIdx.x;   // N*16 threads, 4 elems each
  int n = idx >> 4, q = idx & 15;
  if (n >= N) return;
  float4 v = *(const float4*)(emb0 + (size_t)n * 64 + q * 4);
  st4bf(pk0 + (size_t)n * 256 + q * 4, v);
  st4bf(pk0 + (size_t)n * 256 + 64 + q * 4, v);
}

// ---------------- CSR build ----------------
__global__ void hist_k(const int* __restrict__ h, int* __restrict__ deg, int E) {
  int i = blockIdx.x * blockDim.x + threadIdx.x;
  if (i < E) atomicAdd(&deg[h[i]], 1);
}

__global__ void scanA_k(const int* __restrict__ deg, int* __restrict__ rp,
                        int* __restrict__ sums, int N) {
  __shared__ int s[1024];
  int i = blockIdx.x * 1024 + threadIdx.x;
  int v = (i < N) ? deg[i] : 0;
  s[threadIdx.x] = v;
  __syncthreads();
  for (int off = 1; off < 1024; off <<= 1) {
    int t = (threadIdx.x >= (unsigned)off) ? s[threadIdx.x - off] : 0;
    __syncthreads();
    s[threadIdx.x] += t;
    __syncthreads();
  }
  if (i < N) rp[i] = s[threadIdx.x] - v;
  if (threadIdx.x == 1023) sums[blockIdx.x] = s[1023];
}

__global__ void scanB_k(int* sums, int nch) {
  if (threadIdx.x == 0 && blockIdx.x == 0) {
    int run = 0;
    for (int c = 0; c < nch; c++) { int t = sums[c]; sums[c] = run; run += t; }
  }
}

__global__ void scanC_k(int* __restrict__ rp, int* __restrict__ cur,
                        const int* __restrict__ sums, int N, int E) {
  int i = blockIdx.x * blockDim.x + threadIdx.x;
  if (i < N) {
    int v = rp[i] + sums[i >> 10];
    rp[i] = v; cur[i] = v;
  } else if (i == N) {
    rp[N] = E;
  }
}

__global__ void fill_k(const int* __restrict__ h, int* __restrict__ cur,
                       int* __restrict__ perm, int E) {
  int i = blockIdx.x * blockDim.x + threadIdx.x;
  if (i < E) {
    int pos = atomicAdd(&cur[h[i]], 1);
    perm[pos] = i;
  }
}

// ------- pre-gather edge data into CSR slot order -------
__global__ void pregather_k(const int* __restrict__ perm, const int* __restrict__ t_idx,
                            const float* __restrict__ G, const float* __restrict__ gum,
                            int2* __restrict__ ep, float* __restrict__ cgum,
                            int E, int L) {
  int j = blockIdx.x * blockDim.x + threadIdx.x;
  if (j < E) {
    int pe = perm[j];
    ep[j] = make_int2(t_idx[pe], __float_as_int(G[pe]));
    for (int l = 0; l < L; l++) cgum[(size_t)l * E + j] = gum[(size_t)l * E + pe];
  }
}

// ------- xht: xh[N][64] fp32, xt -> pk[n][192:256] bf16 -------
__global__ __launch_bounds__(256) void xht_k(const float* __restrict__ e,
                                             const float* __restrict__ W,  // [128][64]
                                             float* __restrict__ xh,
                                             unsigned short* __restrict__ pk, int N) {
  __shared__ float et[64 * ST_E];
  __shared__ float wl[64 * ST_WX];
  int tid = threadIdx.x;
  int n0 = blockIdx.x * 64;
  for (int i = tid; i < 64 * 16; i += 256) {
    int r = i >> 4, c4 = (i & 15) * 4;
    float4 v = (n0 + r < N) ? *(const float4*)(e + (size_t)(n0 + r) * 64 + c4) : f4z();
    *(float4*)(et + r * ST_E + c4) = v;
  }
  for (int i = tid; i < 128 * 16; i += 256) {
    int r = i >> 4, c4 = (i & 15) * 4;
    float4 v = *(const float4*)(W + r * 64 + c4);
    if (r < 64) *(float4*)(wl + r * ST_WX + c4) = v;
    else        *(float4*)(wl + (r - 64) * ST_WX + 64 + c4) = v;
  }
  __syncthreads();
  int rg = tid >> 4, tx = tid & 15;
  int s2 = (tx >> 2) * 2;
  float acc[4][8];
#pragma unroll
  for (int i = 0; i < 4; i++)
#pragma unroll
    for (int j = 0; j < 8; j++) acc[i][j] = 0.f;
#pragma unroll 4
  for (int k = 0; k < 64; k++) {
    int kk = (k + s2) & 63;
    float a0 = et[(rg * 4 + 0) * ST_E + kk];
    float a1 = et[(rg * 4 + 1) * ST_E + kk];
    float a2 = et[(rg * 4 + 2) * ST_E + kk];
    float a3 = et[(rg * 4 + 3) * ST_E + kk];
    float4 b0 = *(const float4*)(wl + kk * ST_WX + tx * 8);
    float4 b1 = *(const float4*)(wl + kk * ST_WX + tx * 8 + 4);
    acc[0][0] = fmaf(a0, b0.x, acc[0][0]); acc[0][1] = fmaf(a0, b0.y, acc[0][1]);
    acc[0][2] = fmaf(a0, b0.z, acc[0][2]); acc[0][3] = fmaf(a0, b0.w, acc[0][3]);
    acc[0][4] = fmaf(a0, b1.x, acc[0][4]); acc[0][5] = fmaf(a0, b1.y, acc[0][5]);
    acc[0][6] = fmaf(a0, b1.z, acc[0][6]); acc[0][7] = fmaf(a0, b1.w, acc[0][7]);
    acc[1][0] = fmaf(a1, b0.x, acc[1][0]); acc[1][1] = fmaf(a1, b0.y, acc[1][1]);
    acc[1][2] = fmaf(a1, b0.z, acc[1][2]); acc[1][3] = fmaf(a1, b0.w, acc[1][3]);
    acc[1][4] = fmaf(a1, b1.x, acc[1][4]); acc[1][5] = fmaf(a1, b1.y, acc[1][5]);
    acc[1][6] = fmaf(a1, b1.z, acc[1][6]); acc[1][7] = fmaf(a1, b1.w, acc[1][7]);
    acc[2][0] = fmaf(a2, b0.x, acc[2][0]); acc[2][1] = fmaf(a2, b0.y, acc[2][1]);
    acc[2][2] = fmaf(a2, b0.z, acc[2][2]); acc[2][3] = fmaf(a2, b0.w, acc[2][3]);
    acc[2][4] = fmaf(a2, b1.x, acc[2][4]); acc[2][5] = fmaf(a2, b1.y, acc[2][5]);
    acc[2][6] = fmaf(a2, b1.z, acc[2][6]); acc[2][7] = fmaf(a2, b1.w, acc[2][7]);
    acc[3][0] = fmaf(a3, b0.x, acc[3][0]); acc[3][1] = fmaf(a3, b0.y, acc[3][1]);
    acc[3][2] = fmaf(a3, b0.z, acc[3][2]); acc[3][3] = fmaf(a3, b0.w, acc[3][3]);
    acc[3][4] = fmaf(a3, b1.x, acc[3][4]); acc[3][5] = fmaf(a3, b1.y, acc[3][5]);
    acc[3][6] = fmaf(a3, b1.z, acc[3][6]); acc[3][7] = fmaf(a3, b1.w, acc[3][7]);
  }
#pragma unroll
  for (int i = 0; i < 4; i++) {
    int n = n0 + rg * 4 + i;
    if (n < N) {
      if (tx < 8) {  // xh columns tx*8 .. tx*8+7 (fp32)
        *(float4*)(xh + (size_t)n * 64 + tx * 8) =
            make_float4(acc[i][0], acc[i][1], acc[i][2], acc[i][3]);
        *(float4*)(xh + (size_t)n * 64 + tx * 8 + 4) =
            make_float4(acc[i][4], acc[i][5], acc[i][6], acc[i][7]);
      } else {       // xt columns (tx-8)*8 .. (bf16 -> pk slot 3)
        unsigned short* pp = pk + (size_t)n * 256 + 192 + (tx - 8) * 8;
        st4bf(pp, make_float4(acc[i][0], acc[i][1], acc[i][2], acc[i][3]));
        st4bf(pp + 4, make_float4(acc[i][4], acc[i][5], acc[i][6], acc[i][7]));
      }
    }
  }
}

// ------- node MLP + gate: pk[n][128:192] = bf16(sigmoid(gum+mlp(e))*e) -------
__global__ __launch_bounds__(256) void mlp2_k(const float* __restrict__ e,
    const float* __restrict__ W1, const float* __restrict__ b1,
    const float* __restrict__ W2, const float* __restrict__ b2,
    const float* __restrict__ gum, unsigned short* __restrict__ pk, int N) {
  __shared__ float et[64 * ST_E];
  __shared__ float w1l[64 * ST_W];
  __shared__ float w2l[64 * ST_W];
  __shared__ float ht[64 * ST_E];
  int tid = threadIdx.x;
  int n0 = blockIdx.x * 64;
  for (int i = tid; i < 64 * 16; i += 256) {
    int r = i >> 4, c4 = (i & 15) * 4;
    float4 v = (n0 + r < N) ? *(const float4*)(e + (size_t)(n0 + r) * 64 + c4) : f4z();
    *(float4*)(et + r * ST_E + c4) = v;
    *(float4*)(w1l + r * ST_W + c4) = *(const float4*)(W1 + r * 64 + c4);
    *(float4*)(w2l + r * ST_W + c4) = *(const float4*)(W2 + r * 64 + c4);
  }
  __syncthreads();
  int rg = tid >> 4, tx = tid & 15;
  int s2 = (tx >> 2) * 2;
  float acc[4][4];
#pragma unroll
  for (int i = 0; i < 4; i++)
#pragma unroll
    for (int j = 0; j < 4; j++) acc[i][j] = 0.f;
#pragma unroll 4
  for (int k = 0; k < 64; k++) {
    int kk = (k + s2) & 63;
    float a0 = et[(rg * 4 + 0) * ST_E + kk];
    float a1 = et[(rg * 4 + 1) * ST_E + kk];
    float a2 = et[(rg * 4 + 2) * ST_E + kk];
    float a3 = et[(rg * 4 + 3) * ST_E + kk];
    float4 bv = *(const float4*)(w1l + kk * ST_W + tx * 4);
    acc[0][0] = fmaf(a0, bv.x, acc[0][0]); acc[0][1] = fmaf(a0, bv.y, acc[0][1]);
    acc[0][2] = fmaf(a0, bv.z, acc[0][2]); acc[0][3] = fmaf(a0, bv.w, acc[0][3]);
    acc[1][0] = fmaf(a1, bv.x, acc[1][0]); acc[1][1] = fmaf(a1, bv.y, acc[1][1]);
    acc[1][2] = fmaf(a1, bv.z, acc[1][2]); acc[1][3] = fmaf(a1, bv.w, acc[1][3]);
    acc[2][0] = fmaf(a2, bv.x, acc[2][0]); acc[2][1] = fmaf(a2, bv.y, acc[2][1]);
    acc[2][2] = fmaf(a2, bv.z, acc[2][2]); acc[2][3] = fmaf(a2, bv.w, acc[2][3]);
    acc[3][0] = fmaf(a3, bv.x, acc[3][0]); acc[3][1] = fmaf(a3, bv.y, acc[3][1]);
    acc[3][2] = fmaf(a3, bv.z, acc[3][2]); acc[3][3] = fmaf(a3, bv.w, acc[3][3]);
  }
  float4 b1v = *(const float4*)(b1 + tx * 4);
#pragma unroll
  for (int i = 0; i < 4; i++) {
    float4 hv = make_float4(fmaxf(acc[i][0] + b1v.x, 0.f), fmaxf(acc[i][1] + b1v.y, 0.f),
                            fmaxf(acc[i][2] + b1v.z, 0.f), fmaxf(acc[i][3] + b1v.w, 0.f));
    *(float4*)(ht + (rg * 4 + i) * ST_E + tx * 4) = hv;
  }
  __syncthreads();
  float acc2[4][4];
#pragma unroll
  for (int i = 0; i < 4; i++)
#pragma unroll
    for (int j = 0; j < 4; j++) acc2[i][j] = 0.f;
#pragma unroll 4
  for (int k = 0; k < 64; k++) {
    int kk = (k + s2) & 63;
    float a0 = ht[(rg * 4 + 0) * ST_E + kk];
    float a1 = ht[(rg * 4 + 1) * ST_E + kk];
    float a2 = ht[(rg * 4 + 2) * ST_E + kk];
    float a3 = ht[(rg * 4 + 3) * ST_E + kk];
    float4 bv = *(const float4*)(w2l + kk * ST_W + tx * 4);
    acc2[0][0] = fmaf(a0, bv.x, acc2[0][0]); acc2[0][1] = fmaf(a0, bv.y, acc2[0][1]);
    acc2[0][2] = fmaf(a0, bv.z, acc2[0][2]); acc2[0][3] = fmaf(a0, bv.w, acc2[0][3]);
    acc2[1][0] = fmaf(a1, bv.x, acc2[1][0]); acc2[1][1] = fmaf(a1, bv.y, acc2[1][1]);
    acc2[1][2] = fmaf(a1, bv.z, acc2[1][2]); acc2[1][3] = fmaf(a1, bv.w, acc2[1][3]);
    acc2[2][0] = fmaf(a2, bv.x, acc2[2][0]); acc2[2][1] = fmaf(a2, bv.y, acc2[2][1]);
    acc2[2][2] = fmaf(a2, bv.z, acc2[2][2]); acc2[2][3] = fmaf(a2, bv.w, acc2[2][3]);
    acc2[3][0] = fmaf(a3, bv.x, acc2[3][0]); acc2[3][1] = fmaf(a3, bv.y, acc2[3][1]);
    acc2[3][2] = fmaf(a3, bv.z, acc2[3][2]); acc2[3][3] = fmaf(a3, bv.w, acc2[3][3]);
  }
  float4 b2v = *(const float4*)(b2 + tx * 4);
#pragma unroll
  for (int i = 0; i < 4; i++) {
    int n = n0 + rg * 4 + i;
    if (n < N) {
      float4 gv = *(const float4*)(gum + (size_t)n * 64 + tx * 4);
      float4 ev = *(const float4*)(et + (rg * 4 + i) * ST_E + tx * 4);
      float4 yv;
      yv.x = ev.x / (1.f + expf(-(gv.x + acc2[i][0] + b2v.x)));
      yv.y = ev.y / (1.f + expf(-(gv.y + acc2[i][1] + b2v.y)));
      yv.z = ev.z / (1.f + expf(-(gv.z + acc2[i][2] + b2v.z)));
      yv.w = ev.w / (1.f + expf(-(gv.w + acc2[i][3] + b2v.w)));
      st4bf(pk + (size_t)n * 256 + 128 + tx * 4, yv);
    }
  }
}

// ------- fused 3-branch SpMM + edge-MLP + dinv + residual + sums -------
__global__ __launch_bounds__(256) void spmm3f_k(const int* __restrict__ rp,
    const int2* __restrict__ ep, const float* __restrict__ cgum,
    const unsigned short* __restrict__ pk, const float* __restrict__ xh,
    const float* __restrict__ b1, const float* __restrict__ W2,
    const float* __restrict__ b2,
    const float* __restrict__ ec0, const float* __restrict__ ec1,
    const float* __restrict__ ec2,
    float* __restrict__ e0, float* __restrict__ e1, float* __restrict__ e2,
    unsigned short* __restrict__ pkn,
    float* __restrict__ out0, float* __restrict__ out1, float* __restrict__ out2,
    int first, int N) {
  int g = threadIdx.x >> 4;
  int l = threadIdx.x & 15;
  int n = blockIdx.x * 16 + g;
  if (n >= N) return;
  int jb = rp[n], je = rp[n + 1];
  size_t o = (size_t)n * 64 + l * 4;
  float4 xh4 = *(const float4*)(xh + o);
  float4 b1v = *(const float4*)(b1 + l * 4);
  float4 w2v = *(const float4*)(W2 + l * 4);
  float b2s = b2[0];
  float4 rc0 = *(const float4*)(ec0 + o);
  float4 rc1 = *(const float4*)(ec1 + o);
  float4 rc2 = *(const float4*)(ec2 + o);
  float4 acc0 = f4z(), acc1 = f4z(), acc2 = f4z();
  float wsum = 0.f;
  for (int base = jb; base < je; base += 16) {
    int idx = base + l;
    bool valid = idx < je;
    int2 ev = valid ? ep[idx] : make_int2(0, 0);
    float guv = valid ? cgum[idx] : 0.f;
    int cnt = min(16, je - base);
    for (int i = 0; i < cnt; i++) {
      int t = __shfl(ev.x, i, 16);
      float gg = __shfl(__int_as_float(ev.y), i, 16);
      float gu = __shfl(guv, i, 16);
      const unsigned short* pr = pk + (size_t)t * 256 + l * 4;
      float4 v0 = ldbf4(pr);
      float4 v1 = ldbf4(pr + 64);
      float4 vy = ldbf4(pr + 128);
      float4 xt = ldbf4(pr + 192);
      float p = fmaxf(xh4.x + xt.x + b1v.x, 0.f) * w2v.x
              + fmaxf(xh4.y + xt.y + b1v.y, 0.f) * w2v.y
              + fmaxf(xh4.z + xt.z + b1v.z, 0.f) * w2v.z
              + fmaxf(xh4.w + xt.w + b1v.w, 0.f) * w2v.w;
      p += __shfl_xor(p, 1, 16);
      p += __shfl_xor(p, 2, 16);
      p += __shfl_xor(p, 4, 16);
      p += __shfl_xor(p, 8, 16);
      float w = 1.f / (1.f + expf(-(gu + p + b2s)));
      wsum += w;
      fma4(acc0, gg, v0);
      fma4(acc1, w, v1);
      fma4(acc2, gg, vy);
    }
  }
  float dinv = (wsum > 0.f) ? 1.f / wsum : 0.f;
  float4 en0 = add4(acc0, rc0);
  acc1.x *= dinv; acc1.y *= dinv; acc1.z *= dinv; acc1.w *= dinv;
  float4 en1 = add4(acc1, rc1);
  float4 en2 = add4(acc2, rc2);
  *(float4*)(e0 + o) = en0;
  *(float4*)(e1 + o) = en1;
  *(float4*)(e2 + o) = en2;
  unsigned short* pn = pkn + (size_t)n * 256 + l * 4;
  st4bf(pn, en0);
  st4bf(pn + 64, en1);
  if (first) {
    *(float4*)(out0 + o) = add4(rc0, en0);
    *(float4*)(out1 + o) = add4(rc1, en1);
    *(float4*)(out2 + o) = add4(rc2, en2);
  } else {
    *(float4*)(out0 + o) = add4(*(const float4*)(out0 + o), en0);
    *(float4*)(out1 + o) = add4(*(const float4*)(out1 + o), en1);
    *(float4*)(out2 + o) = add4(*(const float4*)(out2 + o), en2);
  }
}

extern "C" void kernel_launch(void* const* d_in, const int* in_sizes, int n_in,
                              void* d_out, int out_size, void* d_ws, size_t ws_size,
                              hipStream_t stream) {
  const float* emb0        = (const float*)d_in[0];
  const int*   h_idx       = (const int*)d_in[1];
  const int*   t_idx       = (const int*)d_in[2];
  const float* G_values    = (const float*)d_in[3];
  const float* edge_gumbel = (const float*)d_in[4];
  const float* emb_gumbel  = (const float*)d_in[5];
  const float* edge_W1     = (const float*)d_in[6];
  const float* edge_b1     = (const float*)d_in[7];
  const float* edge_W2     = (const float*)d_in[8];
  const float* edge_b2     = (const float*)d_in[9];
  const float* emb_W1      = (const float*)d_in[10];
  const float* emb_b1      = (const float*)d_in[11];
  const float* emb_W2      = (const float*)d_in[12];
  const float* emb_b2      = (const float*)d_in[13];

  const int D = 64;
  const int N = in_sizes[0] / D;
  const int E = in_sizes[1];
  const int L = in_sizes[4] / E;
  const size_t ND = (size_t)N * D;

  char* p = (char*)d_ws;
  auto alloc = [&](size_t bytes) -> char* {
    char* r = p;
    p += (bytes + 255) & ~(size_t)255;
    return r;
  };
  float* e0   = (float*)alloc(ND * 4);
  float* e1   = (float*)alloc(ND * 4);
  float* e2   = (float*)alloc(ND * 4);
  float* xh   = (float*)alloc(ND * 4);
  unsigned short* pkA = (unsigned short*)alloc(ND * 8);   // [N][256] bf16
  unsigned short* pkB = (unsigned short*)alloc(ND * 8);
  int2*  ep    = (int2*)alloc((size_t)E * 8);
  float* cgum  = (float*)alloc((size_t)L * E * 4);
  int*   deg   = (int*)alloc((size_t)N * 4);
  int*   cur   = (int*)alloc((size_t)N * 4);
  int*   rp    = (int*)alloc(((size_t)N + 1) * 4);
  int*   perm  = (int*)alloc((size_t)E * 4);
  int*   sums  = (int*)alloc(1024 * 4);

  float* out = (float*)d_out;

  init_k<<<(N * 16 + 255) / 256, 256, 0, stream>>>(emb0, pkA, N);
  hipMemsetAsync(deg, 0, (size_t)N * 4, stream);
  hist_k<<<(E + 255) / 256, 256, 0, stream>>>(h_idx, deg, E);
  int nch = (N + 1023) / 1024;
  scanA_k<<<nch, 1024, 0, stream>>>(deg, rp, sums, N);
  scanB_k<<<1, 64, 0, stream>>>(sums, nch);
  scanC_k<<<(N + 256) / 256, 256, 0, stream>>>(rp, cur, sums, N, E);
  fill_k<<<(E + 255) / 256, 256, 0, stream>>>(h_idx, cur, perm, E);
  pregather_k<<<(E + 255) / 256, 256, 0, stream>>>(perm, t_idx, G_values,
                                                   edge_gumbel, ep, cgum, E, L);

  int nb64 = (N + 63) / 64;
  int nb16 = (N + 15) / 16;

  for (int i = 0; i < L; i++) {
    unsigned short* pkc = (i & 1) ? pkB : pkA;
    unsigned short* pkn = (i & 1) ? pkA : pkB;
    const float* s1 = (i == 0) ? emb0 : e1;   // e1 state entering layer
    const float* s2 = (i == 0) ? emb0 : e2;
    const float* s0 = (i == 0) ? emb0 : e0;
    xht_k<<<nb64, 256, 0, stream>>>(s1, edge_W1 + (size_t)i * 128 * 64, xh, pkc, N);
    mlp2_k<<<nb64, 256, 0, stream>>>(s2, emb_W1 + (size_t)i * 4096,
                                     emb_b1 + (size_t)i * 64,
                                     emb_W2 + (size_t)i * 4096,
                                     emb_b2 + (size_t)i * 64,
                                     emb_gumbel + (size_t)i * ND, pkc, N);
    spmm3f_k<<<nb16, 256, 0, stream>>>(rp, ep, cgum + (size_t)i * E,
                                       pkc, xh,
                                       edge_b1 + (size_t)i * 64,
                                       edge_W2 + (size_t)i * 64,
                                       edge_b2 + i,
                                       s0, s1, s2,
                                       e0, e1, e2,
                                       pkn,
                                       out, out + ND, out + 2 * ND,
                                       (i == 0) ? 1 : 0, N);
  }
}

// Round 4
// 481.907 us; speedup vs baseline: 3.6334x; 1.1081x over previous
//
#include <hip/hip_runtime.h>
#include <hip/hip_bf16.h>
#include <math.h>

#define ST_E 68
#define ST_W 68
#define ST_WX 132

// pk row layout (elements of bf16): [e0|e1|y2|xt|e2], stride 320
#define SLOT_E0 0
#define SLOT_E1 64
#define SLOT_Y2 128
#define SLOT_XT 192
#define SLOT_E2 256
#define PK_STRIDE 320

__device__ __forceinline__ float4 f4z() { return make_float4(0.f, 0.f, 0.f, 0.f); }
__device__ __forceinline__ void fma4(float4& a, float s, const float4& v) {
  a.x = fmaf(s, v.x, a.x); a.y = fmaf(s, v.y, a.y);
  a.z = fmaf(s, v.z, a.z); a.w = fmaf(s, v.w, a.w);
}
__device__ __forceinline__ float4 add4(const float4& a, const float4& b) {
  return make_float4(a.x + b.x, a.y + b.y, a.z + b.z, a.w + b.w);
}
__device__ __forceinline__ float4 cvt4(const ushort4& u) {
  float4 f;
  f.x = __uint_as_float((unsigned)u.x << 16);
  f.y = __uint_as_float((unsigned)u.y << 16);
  f.z = __uint_as_float((unsigned)u.z << 16);
  f.w = __uint_as_float((unsigned)u.w << 16);
  return f;
}
__device__ __forceinline__ float4 ldbf4(const unsigned short* p) {
  return cvt4(*(const ushort4*)p);
}
__device__ __forceinline__ unsigned short f2bf(float v) {
  __hip_bfloat16 h = __float2bfloat16(v);
  return *reinterpret_cast<unsigned short*>(&h);
}
__device__ __forceinline__ void st4bf(unsigned short* p, const float4& v) {
  ushort4 u;
  u.x = f2bf(v.x); u.y = f2bf(v.y); u.z = f2bf(v.z); u.w = f2bf(v.w);
  *(ushort4*)p = u;
}

// -------- init: pk0 e0/e1/e2 slots = bf16(emb0) --------
__global__ void init_k(const float* __restrict__ emb0, unsigned short* __restrict__ pk0,
                       int N) {
  int idx = blockIdx.x * blockDim.x + threadIdx.x;
  int n = idx >> 4, q = idx & 15;
  if (n >= N) return;
  float4 v = *(const float4*)(emb0 + (size_t)n * 64 + q * 4);
  unsigned short* r = pk0 + (size_t)n * PK_STRIDE + q * 4;
  st4bf(r + SLOT_E0, v);
  st4bf(r + SLOT_E1, v);
  st4bf(r + SLOT_E2, v);
}

// ---------------- CSR build ----------------
__global__ void hist_k(const int* __restrict__ h, int* __restrict__ deg, int E) {
  int i = blockIdx.x * blockDim.x + threadIdx.x;
  if (i < E) atomicAdd(&deg[h[i]], 1);
}

__global__ void scanA_k(const int* __restrict__ deg, int* __restrict__ rp,
                        int* __restrict__ sums, int N) {
  __shared__ int s[1024];
  int i = blockIdx.x * 1024 + threadIdx.x;
  int v = (i < N) ? deg[i] : 0;
  s[threadIdx.x] = v;
  __syncthreads();
  for (int off = 1; off < 1024; off <<= 1) {
    int t = (threadIdx.x >= (unsigned)off) ? s[threadIdx.x - off] : 0;
    __syncthreads();
    s[threadIdx.x] += t;
    __syncthreads();
  }
  if (i < N) rp[i] = s[threadIdx.x] - v;
  if (threadIdx.x == 1023) sums[blockIdx.x] = s[1023];
}

__global__ void scanB_k(int* sums, int nch) {
  if (threadIdx.x == 0 && blockIdx.x == 0) {
    int run = 0;
    for (int c = 0; c < nch; c++) { int t = sums[c]; sums[c] = run; run += t; }
  }
}

__global__ void scanC_k(int* __restrict__ rp, int* __restrict__ cur,
                        const int* __restrict__ sums, int N, int E) {
  int i = blockIdx.x * blockDim.x + threadIdx.x;
  if (i < N) {
    int v = rp[i] + sums[i >> 10];
    rp[i] = v; cur[i] = v;
  } else if (i == N) {
    rp[N] = E;
  }
}

__global__ void fill_k(const int* __restrict__ h, int* __restrict__ cur,
                       int* __restrict__ perm, int E) {
  int i = blockIdx.x * blockDim.x + threadIdx.x;
  if (i < E) {
    int pos = atomicAdd(&cur[h[i]], 1);
    perm[pos] = i;
  }
}

// ------- pre-gather edge data into CSR slot order; t pre-scaled by PK_STRIDE -------
__global__ void pregather_k(const int* __restrict__ perm, const int* __restrict__ t_idx,
                            const float* __restrict__ G, const float* __restrict__ gum,
                            int2* __restrict__ ep, float* __restrict__ cgum,
                            int E, int L) {
  int j = blockIdx.x * blockDim.x + threadIdx.x;
  if (j < E) {
    int pe = perm[j];
    ep[j] = make_int2(t_idx[pe] * PK_STRIDE, __float_as_int(G[pe]));
    for (int l = 0; l < L; l++) cgum[(size_t)l * E + j] = gum[(size_t)l * E + pe];
  }
}

// ------- xht: xh[N][64] fp32, xt -> pk[n] XT slot (reads e1 from pk) -------
__global__ __launch_bounds__(256) void xht_k(const unsigned short* __restrict__ pkin,
                                             const float* __restrict__ W,  // [128][64]
                                             float* __restrict__ xh,
                                             unsigned short* __restrict__ pk, int N) {
  __shared__ float et[64 * ST_E];
  __shared__ float wl[64 * ST_WX];
  int tid = threadIdx.x;
  int n0 = blockIdx.x * 64;
  for (int i = tid; i < 64 * 16; i += 256) {
    int r = i >> 4, c4 = (i & 15) * 4;
    float4 v = (n0 + r < N)
        ? ldbf4(pkin + (size_t)(n0 + r) * PK_STRIDE + SLOT_E1 + c4) : f4z();
    *(float4*)(et + r * ST_E + c4) = v;
  }
  for (int i = tid; i < 128 * 16; i += 256) {
    int r = i >> 4, c4 = (i & 15) * 4;
    float4 v = *(const float4*)(W + r * 64 + c4);
    if (r < 64) *(float4*)(wl + r * ST_WX + c4) = v;
    else        *(float4*)(wl + (r - 64) * ST_WX + 64 + c4) = v;
  }
  __syncthreads();
  int rg = tid >> 4, tx = tid & 15;
  int s2 = (tx >> 2) * 2;
  float acc[4][8];
#pragma unroll
  for (int i = 0; i < 4; i++)
#pragma unroll
    for (int j = 0; j < 8; j++) acc[i][j] = 0.f;
#pragma unroll 4
  for (int k = 0; k < 64; k++) {
    int kk = (k + s2) & 63;
    float a0 = et[(rg * 4 + 0) * ST_E + kk];
    float a1 = et[(rg * 4 + 1) * ST_E + kk];
    float a2 = et[(rg * 4 + 2) * ST_E + kk];
    float a3 = et[(rg * 4 + 3) * ST_E + kk];
    float4 b0 = *(const float4*)(wl + kk * ST_WX + tx * 8);
    float4 b1 = *(const float4*)(wl + kk * ST_WX + tx * 8 + 4);
    acc[0][0] = fmaf(a0, b0.x, acc[0][0]); acc[0][1] = fmaf(a0, b0.y, acc[0][1]);
    acc[0][2] = fmaf(a0, b0.z, acc[0][2]); acc[0][3] = fmaf(a0, b0.w, acc[0][3]);
    acc[0][4] = fmaf(a0, b1.x, acc[0][4]); acc[0][5] = fmaf(a0, b1.y, acc[0][5]);
    acc[0][6] = fmaf(a0, b1.z, acc[0][6]); acc[0][7] = fmaf(a0, b1.w, acc[0][7]);
    acc[1][0] = fmaf(a1, b0.x, acc[1][0]); acc[1][1] = fmaf(a1, b0.y, acc[1][1]);
    acc[1][2] = fmaf(a1, b0.z, acc[1][2]); acc[1][3] = fmaf(a1, b0.w, acc[1][3]);
    acc[1][4] = fmaf(a1, b1.x, acc[1][4]); acc[1][5] = fmaf(a1, b1.y, acc[1][5]);
    acc[1][6] = fmaf(a1, b1.z, acc[1][6]); acc[1][7] = fmaf(a1, b1.w, acc[1][7]);
    acc[2][0] = fmaf(a2, b0.x, acc[2][0]); acc[2][1] = fmaf(a2, b0.y, acc[2][1]);
    acc[2][2] = fmaf(a2, b0.z, acc[2][2]); acc[2][3] = fmaf(a2, b0.w, acc[2][3]);
    acc[2][4] = fmaf(a2, b1.x, acc[2][4]); acc[2][5] = fmaf(a2, b1.y, acc[2][5]);
    acc[2][6] = fmaf(a2, b1.z, acc[2][6]); acc[2][7] = fmaf(a2, b1.w, acc[2][7]);
    acc[3][0] = fmaf(a3, b0.x, acc[3][0]); acc[3][1] = fmaf(a3, b0.y, acc[3][1]);
    acc[3][2] = fmaf(a3, b0.z, acc[3][2]); acc[3][3] = fmaf(a3, b0.w, acc[3][3]);
    acc[3][4] = fmaf(a3, b1.x, acc[3][4]); acc[3][5] = fmaf(a3, b1.y, acc[3][5]);
    acc[3][6] = fmaf(a3, b1.z, acc[3][6]); acc[3][7] = fmaf(a3, b1.w, acc[3][7]);
  }
#pragma unroll
  for (int i = 0; i < 4; i++) {
    int n = n0 + rg * 4 + i;
    if (n < N) {
      if (tx < 8) {
        *(float4*)(xh + (size_t)n * 64 + tx * 8) =
            make_float4(acc[i][0], acc[i][1], acc[i][2], acc[i][3]);
        *(float4*)(xh + (size_t)n * 64 + tx * 8 + 4) =
            make_float4(acc[i][4], acc[i][5], acc[i][6], acc[i][7]);
      } else {
        unsigned short* pp = pk + (size_t)n * PK_STRIDE + SLOT_XT + (tx - 8) * 8;
        st4bf(pp, make_float4(acc[i][0], acc[i][1], acc[i][2], acc[i][3]));
        st4bf(pp + 4, make_float4(acc[i][4], acc[i][5], acc[i][6], acc[i][7]));
      }
    }
  }
}

// ------- node MLP + gate: pk Y2 slot = bf16(sigmoid(gum+mlp(e2))*e2) -------
__global__ __launch_bounds__(256) void mlp2_k(const unsigned short* __restrict__ pkin,
    const float* __restrict__ W1, const float* __restrict__ b1,
    const float* __restrict__ W2, const float* __restrict__ b2,
    const float* __restrict__ gum, unsigned short* __restrict__ pk, int N) {
  __shared__ float et[64 * ST_E];
  __shared__ float w1l[64 * ST_W];
  __shared__ float w2l[64 * ST_W];
  __shared__ float ht[64 * ST_E];
  int tid = threadIdx.x;
  int n0 = blockIdx.x * 64;
  for (int i = tid; i < 64 * 16; i += 256) {
    int r = i >> 4, c4 = (i & 15) * 4;
    float4 v = (n0 + r < N)
        ? ldbf4(pkin + (size_t)(n0 + r) * PK_STRIDE + SLOT_E2 + c4) : f4z();
    *(float4*)(et + r * ST_E + c4) = v;
    *(float4*)(w1l + r * ST_W + c4) = *(const float4*)(W1 + r * 64 + c4);
    *(float4*)(w2l + r * ST_W + c4) = *(const float4*)(W2 + r * 64 + c4);
  }
  __syncthreads();
  int rg = tid >> 4, tx = tid & 15;
  int s2 = (tx >> 2) * 2;
  float acc[4][4];
#pragma unroll
  for (int i = 0; i < 4; i++)
#pragma unroll
    for (int j = 0; j < 4; j++) acc[i][j] = 0.f;
#pragma unroll 4
  for (int k = 0; k < 64; k++) {
    int kk = (k + s2) & 63;
    float a0 = et[(rg * 4 + 0) * ST_E + kk];
    float a1 = et[(rg * 4 + 1) * ST_E + kk];
    float a2 = et[(rg * 4 + 2) * ST_E + kk];
    float a3 = et[(rg * 4 + 3) * ST_E + kk];
    float4 bv = *(const float4*)(w1l + kk * ST_W + tx * 4);
    acc[0][0] = fmaf(a0, bv.x, acc[0][0]); acc[0][1] = fmaf(a0, bv.y, acc[0][1]);
    acc[0][2] = fmaf(a0, bv.z, acc[0][2]); acc[0][3] = fmaf(a0, bv.w, acc[0][3]);
    acc[1][0] = fmaf(a1, bv.x, acc[1][0]); acc[1][1] = fmaf(a1, bv.y, acc[1][1]);
    acc[1][2] = fmaf(a1, bv.z, acc[1][2]); acc[1][3] = fmaf(a1, bv.w, acc[1][3]);
    acc[2][0] = fmaf(a2, bv.x, acc[2][0]); acc[2][1] = fmaf(a2, bv.y, acc[2][1]);
    acc[2][2] = fmaf(a2, bv.z, acc[2][2]); acc[2][3] = fmaf(a2, bv.w, acc[2][3]);
    acc[3][0] = fmaf(a3, bv.x, acc[3][0]); acc[3][1] = fmaf(a3, bv.y, acc[3][1]);
    acc[3][2] = fmaf(a3, bv.z, acc[3][2]); acc[3][3] = fmaf(a3, bv.w, acc[3][3]);
  }
  float4 b1v = *(const float4*)(b1 + tx * 4);
#pragma unroll
  for (int i = 0; i < 4; i++) {
    float4 hv = make_float4(fmaxf(acc[i][0] + b1v.x, 0.f), fmaxf(acc[i][1] + b1v.y, 0.f),
                            fmaxf(acc[i][2] + b1v.z, 0.f), fmaxf(acc[i][3] + b1v.w, 0.f));
    *(float4*)(ht + (rg * 4 + i) * ST_E + tx * 4) = hv;
  }
  __syncthreads();
  float acc2[4][4];
#pragma unroll
  for (int i = 0; i < 4; i++)
#pragma unroll
    for (int j = 0; j < 4; j++) acc2[i][j] = 0.f;
#pragma unroll 4
  for (int k = 0; k < 64; k++) {
    int kk = (k + s2) & 63;
    float a0 = ht[(rg * 4 + 0) * ST_E + kk];
    float a1 = ht[(rg * 4 + 1) * ST_E + kk];
    float a2 = ht[(rg * 4 + 2) * ST_E + kk];
    float a3 = ht[(rg * 4 + 3) * ST_E + kk];
    float4 bv = *(const float4*)(w2l + kk * ST_W + tx * 4);
    acc2[0][0] = fmaf(a0, bv.x, acc2[0][0]); acc2[0][1] = fmaf(a0, bv.y, acc2[0][1]);
    acc2[0][2] = fmaf(a0, bv.z, acc2[0][2]); acc2[0][3] = fmaf(a0, bv.w, acc2[0][3]);
    acc2[1][0] = fmaf(a1, bv.x, acc2[1][0]); acc2[1][1] = fmaf(a1, bv.y, acc2[1][1]);
    acc2[1][2] = fmaf(a1, bv.z, acc2[1][2]); acc2[1][3] = fmaf(a1, bv.w, acc2[1][3]);
    acc2[2][0] = fmaf(a2, bv.x, acc2[2][0]); acc2[2][1] = fmaf(a2, bv.y, acc2[2][1]);
    acc2[2][2] = fmaf(a2, bv.z, acc2[2][2]); acc2[2][3] = fmaf(a2, bv.w, acc2[2][3]);
    acc2[3][0] = fmaf(a3, bv.x, acc2[3][0]); acc2[3][1] = fmaf(a3, bv.y, acc2[3][1]);
    acc2[3][2] = fmaf(a3, bv.z, acc2[3][2]); acc2[3][3] = fmaf(a3, bv.w, acc2[3][3]);
  }
  float4 b2v = *(const float4*)(b2 + tx * 4);
#pragma unroll
  for (int i = 0; i < 4; i++) {
    int n = n0 + rg * 4 + i;
    if (n < N) {
      float4 gv = *(const float4*)(gum + (size_t)n * 64 + tx * 4);
      float4 ev = *(const float4*)(et + (rg * 4 + i) * ST_E + tx * 4);
      float4 yv;
      yv.x = ev.x / (1.f + expf(-(gv.x + acc2[i][0] + b2v.x)));
      yv.y = ev.y / (1.f + expf(-(gv.y + acc2[i][1] + b2v.y)));
      yv.z = ev.z / (1.f + expf(-(gv.z + acc2[i][2] + b2v.z)));
      yv.w = ev.w / (1.f + expf(-(gv.w + acc2[i][3] + b2v.w)));
      st4bf(pk + (size_t)n * PK_STRIDE + SLOT_Y2 + tx * 4, yv);
    }
  }
}

// ------- fused 3-branch SpMM + edge-MLP + dinv + residual + out -------
// OUTM: 0 = no out;  1 = out = emb0 + rc + en (L=2 final);
//       2 = out = rc + en (generic first); 3 = out += en (generic accumulate)
template <int FIRST, int OUTM>
__global__ __launch_bounds__(256) void spmm3f_k(const int* __restrict__ rp,
    const int2* __restrict__ ep, const float* __restrict__ cgum,
    const unsigned short* __restrict__ pk, const float* __restrict__ xh,
    const float* __restrict__ b1, const float* __restrict__ W2,
    const float* __restrict__ b2, const float* __restrict__ emb0,
    unsigned short* __restrict__ pkn,
    float* __restrict__ out0, float* __restrict__ out1, float* __restrict__ out2,
    int N) {
  int g = threadIdx.x >> 4;
  int l = threadIdx.x & 15;
  int n = blockIdx.x * 16 + g;
  if (n >= N) return;
  int jb = rp[n], je = rp[n + 1];
  size_t o64 = (size_t)n * 64 + l * 4;
  size_t opk = (size_t)n * PK_STRIDE + l * 4;
  float4 xh4 = *(const float4*)(xh + o64);
  float4 b1v = *(const float4*)(b1 + l * 4);
  float4 w2v = *(const float4*)(W2 + l * 4);
  float b2s = b2[0];
  float4 rc0, rc1, rc2;
  if (FIRST) {
    rc0 = *(const float4*)(emb0 + o64);
    rc1 = rc0; rc2 = rc0;
  } else {
    rc0 = ldbf4(pk + opk + SLOT_E0);
    rc1 = ldbf4(pk + opk + SLOT_E1);
    rc2 = ldbf4(pk + opk + SLOT_E2);
  }
  float4 acc0 = f4z(), acc1 = f4z(), acc2 = f4z();
  float wsum = 0.f;
  for (int base = jb; base < je; base += 16) {
    int idx = base + l;
    bool valid = idx < je;
    int2 ev = valid ? ep[idx] : make_int2(0, 0);
    float guv = valid ? cgum[idx] : 0.f;
    int cnt = min(16, je - base);
    // prime edge 0
    int toff = __shfl(ev.x, 0, 16);
    const unsigned short* pr = pk + (size_t)toff + l * 4;
    ushort4 a0 = *(const ushort4*)(pr + SLOT_E0);
    ushort4 a1;
    if (!FIRST) a1 = *(const ushort4*)(pr + SLOT_E1);
    ushort4 a2 = *(const ushort4*)(pr + SLOT_Y2);
    ushort4 a3 = *(const ushort4*)(pr + SLOT_XT);
    for (int i = 0; i < cnt; i++) {
      ushort4 p0, p1, p2, p3;
      bool pf = (i + 1 < cnt);
      if (pf) {
        int toff2 = __shfl(ev.x, i + 1, 16);
        const unsigned short* pr2 = pk + (size_t)toff2 + l * 4;
        p0 = *(const ushort4*)(pr2 + SLOT_E0);
        if (!FIRST) p1 = *(const ushort4*)(pr2 + SLOT_E1);
        p2 = *(const ushort4*)(pr2 + SLOT_Y2);
        p3 = *(const ushort4*)(pr2 + SLOT_XT);
      }
      float gg = __shfl(__int_as_float(ev.y), i, 16);
      float gu = __shfl(guv, i, 16);
      float4 v0 = cvt4(a0);
      float4 v1 = FIRST ? v0 : cvt4(a1);
      float4 vy = cvt4(a2);
      float4 xt = cvt4(a3);
      float p = fmaxf(xh4.x + xt.x + b1v.x, 0.f) * w2v.x
              + fmaxf(xh4.y + xt.y + b1v.y, 0.f) * w2v.y
              + fmaxf(xh4.z + xt.z + b1v.z, 0.f) * w2v.z
              + fmaxf(xh4.w + xt.w + b1v.w, 0.f) * w2v.w;
      p += __shfl_xor(p, 1, 16);
      p += __shfl_xor(p, 2, 16);
      p += __shfl_xor(p, 4, 16);
      p += __shfl_xor(p, 8, 16);
      float w = 1.f / (1.f + expf(-(gu + p + b2s)));
      wsum += w;
      fma4(acc0, gg, v0);
      fma4(acc1, w, v1);
      fma4(acc2, gg, vy);
      if (pf) { a0 = p0; if (!FIRST) a1 = p1; a2 = p2; a3 = p3; }
    }
  }
  float dinv = (wsum > 0.f) ? 1.f / wsum : 0.f;
  float4 en0 = add4(acc0, rc0);
  acc1.x *= dinv; acc1.y *= dinv; acc1.z *= dinv; acc1.w *= dinv;
  float4 en1 = add4(acc1, rc1);
  float4 en2 = add4(acc2, rc2);
  unsigned short* pn = pkn + opk;
  st4bf(pn + SLOT_E0, en0);
  st4bf(pn + SLOT_E1, en1);
  st4bf(pn + SLOT_E2, en2);
  if (OUTM == 1) {
    float4 base = *(const float4*)(emb0 + o64);
    *(float4*)(out0 + o64) = add4(base, add4(rc0, en0));
    *(float4*)(out1 + o64) = add4(base, add4(rc1, en1));
    *(float4*)(out2 + o64) = add4(base, add4(rc2, en2));
  } else if (OUTM == 2) {
    *(float4*)(out0 + o64) = add4(rc0, en0);
    *(float4*)(out1 + o64) = add4(rc1, en1);
    *(float4*)(out2 + o64) = add4(rc2, en2);
  } else if (OUTM == 3) {
    *(float4*)(out0 + o64) = add4(*(const float4*)(out0 + o64), en0);
    *(float4*)(out1 + o64) = add4(*(const float4*)(out1 + o64), en1);
    *(float4*)(out2 + o64) = add4(*(const float4*)(out2 + o64), en2);
  }
}

extern "C" void kernel_launch(void* const* d_in, const int* in_sizes, int n_in,
                              void* d_out, int out_size, void* d_ws, size_t ws_size,
                              hipStream_t stream) {
  const float* emb0        = (const float*)d_in[0];
  const int*   h_idx       = (const int*)d_in[1];
  const int*   t_idx       = (const int*)d_in[2];
  const float* G_values    = (const float*)d_in[3];
  const float* edge_gumbel = (const float*)d_in[4];
  const float* emb_gumbel  = (const float*)d_in[5];
  const float* edge_W1     = (const float*)d_in[6];
  const float* edge_b1     = (const float*)d_in[7];
  const float* edge_W2     = (const float*)d_in[8];
  const float* edge_b2     = (const float*)d_in[9];
  const float* emb_W1      = (const float*)d_in[10];
  const float* emb_b1      = (const float*)d_in[11];
  const float* emb_W2      = (const float*)d_in[12];
  const float* emb_b2      = (const float*)d_in[13];

  const int D = 64;
  const int N = in_sizes[0] / D;
  const int E = in_sizes[1];
  const int L = in_sizes[4] / E;
  const size_t ND = (size_t)N * D;

  char* p = (char*)d_ws;
  auto alloc = [&](size_t bytes) -> char* {
    char* r = p;
    p += (bytes + 255) & ~(size_t)255;
    return r;
  };
  float* xh   = (float*)alloc(ND * 4);
  unsigned short* pkA = (unsigned short*)alloc((size_t)N * PK_STRIDE * 2);
  unsigned short* pkB = (unsigned short*)alloc((size_t)N * PK_STRIDE * 2);
  int2*  ep    = (int2*)alloc((size_t)E * 8);
  float* cgum  = (float*)alloc((size_t)L * E * 4);
  int*   deg   = (int*)alloc((size_t)N * 4);
  int*   cur   = (int*)alloc((size_t)N * 4);
  int*   rp    = (int*)alloc(((size_t)N + 1) * 4);
  int*   perm  = (int*)alloc((size_t)E * 4);
  int*   sums  = (int*)alloc(1024 * 4);

  float* out = (float*)d_out;

  init_k<<<(N * 16 + 255) / 256, 256, 0, stream>>>(emb0, pkA, N);
  hipMemsetAsync(deg, 0, (size_t)N * 4, stream);
  hist_k<<<(E + 255) / 256, 256, 0, stream>>>(h_idx, deg, E);
  int nch = (N + 1023) / 1024;
  scanA_k<<<nch, 1024, 0, stream>>>(deg, rp, sums, N);
  scanB_k<<<1, 64, 0, stream>>>(sums, nch);
  scanC_k<<<(N + 256) / 256, 256, 0, stream>>>(rp, cur, sums, N, E);
  fill_k<<<(E + 255) / 256, 256, 0, stream>>>(h_idx, cur, perm, E);
  pregather_k<<<(E + 255) / 256, 256, 0, stream>>>(perm, t_idx, G_values,
                                                   edge_gumbel, ep, cgum, E, L);

  int nb64 = (N + 63) / 64;
  int nb16 = (N + 15) / 16;

  for (int i = 0; i < L; i++) {
    unsigned short* pkc = (i & 1) ? pkB : pkA;
    unsigned short* pkn = (i & 1) ? pkA : pkB;
    xht_k<<<nb64, 256, 0, stream>>>(pkc, edge_W1 + (size_t)i * 128 * 64, xh, pkc, N);
    mlp2_k<<<nb64, 256, 0, stream>>>(pkc, emb_W1 + (size_t)i * 4096,
                                     emb_b1 + (size_t)i * 64,
                                     emb_W2 + (size_t)i * 4096,
                                     emb_b2 + (size_t)i * 64,
                                     emb_gumbel + (size_t)i * ND, pkc, N);
    const float* cg = cgum + (size_t)i * E;
    const float* eb1 = edge_b1 + (size_t)i * 64;
    const float* eW2 = edge_W2 + (size_t)i * 64;
    const float* eb2 = edge_b2 + i;
    if (L == 2) {
      if (i == 0)
        spmm3f_k<1, 0><<<nb16, 256, 0, stream>>>(rp, ep, cg, pkc, xh, eb1, eW2, eb2,
                                                 emb0, pkn, out, out + ND, out + 2 * ND, N);
      else
        spmm3f_k<0, 1><<<nb16, 256, 0, stream>>>(rp, ep, cg, pkc, xh, eb1, eW2, eb2,
                                                 emb0, pkn, out, out + ND, out + 2 * ND, N);
    } else {
      if (i == 0)
        spmm3f_k<1, 2><<<nb16, 256, 0, stream>>>(rp, ep, cg, pkc, xh, eb1, eW2, eb2,
                                                 emb0, pkn, out, out + ND, out + 2 * ND, N);
      else
        spmm3f_k<0, 3><<<nb16, 256, 0, stream>>>(rp, ep, cg, pkc, xh, eb1, eW2, eb2,
                                                 emb0, pkn, out, out + ND, out + 2 * ND, N);
    }
  }
}